// Round 10
// baseline (226.497 us; speedup 1.0000x reference)
//
#include <hip/hip_runtime.h>
#include <math.h>

// GCN 2-layer on [N,1] collapses to scalar passes:
//   dis[i] = 1/sqrt(1 + indeg[i]);  g[i] = dis[i]*x[i]
//   s[c]   = dis[c]*(g[c] + sum_{e->c} g[row_e])
//   h[i]   = alpha*s[i] + beta   (alpha = W1.W2, beta = b1.W2)
//   g2[i]  = dis[i]*h[i]
//   out[c] = dis[c]*(g2[c] + sum_{e->c} g2[row_e]) + b2
//
// r10: acc2/acc3 random gathers (64 lines per wave-load, TA-serialized)
// replaced by row-group LDS staging: bucket edges copied to LDS once
// (scan-indexed, no atomics), then 13 phases of {stage 8192 g values
// coalesced -> LDS, scan ebuf, accumulate from LDS}. place/acc1 as r9.

#define CHUNK 256
#define CHUNK_SHIFT 8
#define PACK_SHIFT 17              // low 17 bits: row (N <= 131072)
#define ROW_MASK ((1u << PACK_SHIFT) - 1u)
#define NBMAX 512
#define SLICES 256                 // == k_place grid size
#define CAPB 80                    // slice capacity; mean 32, 8.4 sigma margin
#define CAPB_V (CAPB / 4)          // 20 uint4 slots per slice
#define TPB 512
#define PLACE_TPB 1024
#define RG_BITS 13
#define RG_SIZE (1 << RG_BITS)     // 8192 rows staged per phase (32 KB)
#define RG_MASK (RG_SIZE - 1)
#define EBUF_CAP 9216              // bucket mean 8184, sigma ~90 -> 11 sigma

static __device__ __forceinline__ int gid() {
    return blockIdx.x * blockDim.x + threadIdx.x;
}

// ---- place: single-pass static-slice scatter (r9, proven) ----------------
__global__ void __launch_bounds__(PLACE_TPB)
k_place(const int* __restrict__ row, const int* __restrict__ col,
        int E, int NB, int* __restrict__ len, unsigned* __restrict__ sorted) {
    __shared__ int cnt[NBMAX];
    const int tid = threadIdx.x;
    const int blk = blockIdx.x;
    for (int t = tid; t < NB; t += PLACE_TPB) cnt[t] = 0;
    __syncthreads();
    int quads = E >> 2;
    int per = (quads + gridDim.x - 1) / gridDim.x;
    int qlo = blk * per, qhi = min(quads, qlo + per);
    for (int q = qlo + tid; q < qhi; q += PLACE_TPB) {
        int4 r = reinterpret_cast<const int4*>(row)[q];
        int4 c = reinterpret_cast<const int4*>(col)[q];
        {
            int b = c.x >> CHUNK_SHIFT;
            int i = atomicAdd(&cnt[b], 1);
            if (i < CAPB)
                sorted[((size_t)b * SLICES + blk) * CAPB + i] =
                    (unsigned)r.x | ((unsigned)(c.x & (CHUNK - 1)) << PACK_SHIFT);
        }
        {
            int b = c.y >> CHUNK_SHIFT;
            int i = atomicAdd(&cnt[b], 1);
            if (i < CAPB)
                sorted[((size_t)b * SLICES + blk) * CAPB + i] =
                    (unsigned)r.y | ((unsigned)(c.y & (CHUNK - 1)) << PACK_SHIFT);
        }
        {
            int b = c.z >> CHUNK_SHIFT;
            int i = atomicAdd(&cnt[b], 1);
            if (i < CAPB)
                sorted[((size_t)b * SLICES + blk) * CAPB + i] =
                    (unsigned)r.z | ((unsigned)(c.z & (CHUNK - 1)) << PACK_SHIFT);
        }
        {
            int b = c.w >> CHUNK_SHIFT;
            int i = atomicAdd(&cnt[b], 1);
            if (i < CAPB)
                sorted[((size_t)b * SLICES + blk) * CAPB + i] =
                    (unsigned)r.w | ((unsigned)(c.w & (CHUNK - 1)) << PACK_SHIFT);
        }
    }
    // tail edges (E % 4): appended to block 0's own slices
    if (blk == 0 && tid == 0) {
        for (int j = quads << 2; j < E; ++j) {
            int cc = col[j];
            int b = cc >> CHUNK_SHIFT;
            int i = atomicAdd(&cnt[b], 1);
            if (i < CAPB)
                sorted[((size_t)b * SLICES) * CAPB + i] =
                    (unsigned)row[j] | ((unsigned)(cc & (CHUNK - 1)) << PACK_SHIFT);
        }
    }
    __syncthreads();
    for (int t = tid; t < NB; t += PLACE_TPB)
        len[(size_t)t * SLICES + blk] = min(cnt[t], CAPB);
}

// ---- acc1: degree count + dis,g (no gathers; r9 structure) ---------------
__global__ void __launch_bounds__(TPB)
k_acc1(const unsigned* __restrict__ sorted, const int* __restrict__ len,
       const float* __restrict__ x, float* __restrict__ dis, float* __restrict__ g,
       int N) {
    __shared__ float acc[CHUNK];
    __shared__ int slen[SLICES];
    const int b = blockIdx.x;
    const int tid = threadIdx.x;
    if (tid < CHUNK) acc[tid] = 0.0f;
    for (int t = tid; t < SLICES; t += TPB) slen[t] = len[(size_t)b * SLICES + t];
    __syncthreads();
    const uint4* bs = reinterpret_cast<const uint4*>(sorted + (size_t)b * SLICES * CAPB);
    const int TOTV = SLICES * CAPB_V;
    for (int j = tid; j < TOTV; j += TPB) {
        int s = j / CAPB_V;
        int l = slen[s];
        int base = (j - s * CAPB_V) << 2;
        if (base >= l) continue;
        uint4 p = bs[j];
        atomicAdd(&acc[p.x >> PACK_SHIFT], 1.0f);
        if (base + 1 < l) atomicAdd(&acc[p.y >> PACK_SHIFT], 1.0f);
        if (base + 2 < l) atomicAdd(&acc[p.z >> PACK_SHIFT], 1.0f);
        if (base + 3 < l) atomicAdd(&acc[p.w >> PACK_SHIFT], 1.0f);
    }
    __syncthreads();
    int i = b * CHUNK + tid;
    if (tid < CHUNK && i < N) {
        float d = rsqrtf(1.0f + acc[tid]);  // +1: self-loop
        dis[i] = d;
        g[i] = d * x[i];
    }
}

// ---- acc2/acc3 core: bucket edges -> LDS; row-group staged accumulation --
// Shared implementation via a device function; VAL = g (acc2) or g2 (acc3).

static __device__ __forceinline__ void
acc_staged(const unsigned* __restrict__ sorted, const int* __restrict__ len,
           const float* __restrict__ val, int RG_CNT, int b, int tid,
           unsigned* ebuf, float* gstage, int* slen, int* soff, float* acc, int N) {
    if (tid < CHUNK) acc[tid] = 0.0f;
    for (int t = tid; t < SLICES; t += TPB) slen[t] = len[(size_t)b * SLICES + t];
    __syncthreads();
    // inclusive Hillis-Steele scan of slen -> soff
    if (tid < SLICES) soff[tid] = slen[tid];
    __syncthreads();
    for (int off = 1; off < SLICES; off <<= 1) {
        int v = 0;
        if (tid < SLICES) {
            v = soff[tid];
            if (tid >= off) v += soff[tid - off];
        }
        __syncthreads();
        if (tid < SLICES) soff[tid] = v;
        __syncthreads();
    }
    // load bucket entries into ebuf at scan-derived positions (no atomics)
    const uint4* bs = reinterpret_cast<const uint4*>(sorted + (size_t)b * SLICES * CAPB);
    const int TOTV = SLICES * CAPB_V;
    for (int j = tid; j < TOTV; j += TPB) {
        int s = j / CAPB_V;
        int l = slen[s];
        int base = (j - s * CAPB_V) << 2;
        if (base >= l) continue;
        uint4 p = bs[j];
        int e0 = soff[s] - l + base;  // exclusive offset + position
        if (e0 < EBUF_CAP) ebuf[e0] = p.x;
        if (base + 1 < l && e0 + 1 < EBUF_CAP) ebuf[e0 + 1] = p.y;
        if (base + 2 < l && e0 + 2 < EBUF_CAP) ebuf[e0 + 2] = p.z;
        if (base + 3 < l && e0 + 3 < EBUF_CAP) ebuf[e0 + 3] = p.w;
    }
    __syncthreads();
    int blen = min(soff[SLICES - 1], EBUF_CAP);
    // phases: stage one row-group of val, accumulate matching entries
    for (int rg = 0; rg < RG_CNT; ++rg) {
        int rbase = rg << RG_BITS;
        for (int t = tid; t < RG_SIZE; t += TPB) {
            int r = rbase + t;
            gstage[t] = (r < N) ? val[r] : 0.0f;
        }
        __syncthreads();
        for (int j = tid; j < blen; j += TPB) {
            unsigned e = ebuf[j];
            unsigned r = e & ROW_MASK;
            if ((int)(r >> RG_BITS) == rg)
                atomicAdd(&acc[e >> PACK_SHIFT], gstage[r & RG_MASK]);
        }
        __syncthreads();
    }
}

__global__ void __launch_bounds__(TPB)
k_acc2(const unsigned* __restrict__ sorted, const int* __restrict__ len,
       const float* __restrict__ g, const float* __restrict__ dis,
       const float* __restrict__ W1, const float* __restrict__ b1,
       const float* __restrict__ W2, int H, int RG_CNT,
       float* __restrict__ g2, int N) {
    __shared__ unsigned ebuf[EBUF_CAP];
    __shared__ float gstage[RG_SIZE];
    __shared__ int slen[SLICES];
    __shared__ int soff[SLICES];
    __shared__ float acc[CHUNK];
    __shared__ float sab[2];
    const int b = blockIdx.x;
    const int tid = threadIdx.x;
    if (tid >= CHUNK && tid < CHUNK + 64) {  // one wave: alpha, beta (H<=64)
        int t = tid - CHUNK;
        float w2 = (t < H) ? W2[t] : 0.0f;
        float a = (t < H) ? W1[t] * w2 : 0.0f;
        float bb = (t < H) ? b1[t] * w2 : 0.0f;
        for (int o = 32; o; o >>= 1) {
            a += __shfl_down(a, o, 64);
            bb += __shfl_down(bb, o, 64);
        }
        if (t == 0) { sab[0] = a; sab[1] = bb; }
    }
    acc_staged(sorted, len, g, RG_CNT, b, tid, ebuf, gstage, slen, soff, acc, N);
    int i = b * CHUNK + tid;
    if (tid < CHUNK && i < N) {
        float d = dis[i];
        float s = d * (g[i] + acc[tid]);
        g2[i] = d * (sab[0] * s + sab[1]);
    }
}

__global__ void __launch_bounds__(TPB)
k_acc3(const unsigned* __restrict__ sorted, const int* __restrict__ len,
       const float* __restrict__ g2, const float* __restrict__ dis,
       const float* __restrict__ b2, int RG_CNT, float* __restrict__ out, int N) {
    __shared__ unsigned ebuf[EBUF_CAP];
    __shared__ float gstage[RG_SIZE];
    __shared__ int slen[SLICES];
    __shared__ int soff[SLICES];
    __shared__ float acc[CHUNK];
    const int b = blockIdx.x;
    const int tid = threadIdx.x;
    acc_staged(sorted, len, g2, RG_CNT, b, tid, ebuf, gstage, slen, soff, acc, N);
    int i = b * CHUNK + tid;
    if (tid < CHUNK && i < N)
        out[i] = dis[i] * (g2[i] + acc[tid]) + b2[0];
}

// ---- fallback (plain device atomics, known-correct) ----------------------

__global__ void k_zero_f(float* __restrict__ p, int n) {
    int i = gid();
    if (i < n) p[i] = 0.0f;
}

__global__ void k_ab_fb(const float* __restrict__ W1, const float* __restrict__ b1,
                        const float* __restrict__ W2, float* __restrict__ ab, int hidden) {
    int t = threadIdx.x;
    float w2 = (t < hidden) ? W2[t] : 0.0f;
    float a = (t < hidden) ? W1[t] * w2 : 0.0f;
    float b = (t < hidden) ? b1[t] * w2 : 0.0f;
    for (int o = 32; o; o >>= 1) {
        a += __shfl_down(a, o, 64);
        b += __shfl_down(b, o, 64);
    }
    if (t == 0) { ab[0] = a; ab[1] = b; }
}

__global__ void k_deg_fb(const int* __restrict__ col, float* __restrict__ t, int E) {
    int i = gid();
    if (i < E) atomicAdd(&t[col[i]], 1.0f);
}

__global__ void k_scat_fb(const int* __restrict__ ei, const float* __restrict__ val,
                          float* __restrict__ t, int E) {
    int i = gid();
    if (i < E) atomicAdd(&t[ei[E + i]], val[ei[i]]);
}

__global__ void k_node1_fb(const float* __restrict__ x, const float* __restrict__ degsum,
                           float* __restrict__ dis, float* __restrict__ g, int N) {
    int i = gid();
    if (i < N) {
        float d = rsqrtf(1.0f + degsum[i]);
        dis[i] = d;
        g[i] = d * x[i];
    }
}

__global__ void k_node2_fb(const float* __restrict__ g, const float* __restrict__ dis,
                           const float* __restrict__ ab, const float* __restrict__ sum1,
                           float* __restrict__ g2, int N) {
    int i = gid();
    if (i < N) {
        float s = dis[i] * (g[i] + sum1[i]);
        g2[i] = dis[i] * (ab[0] * s + ab[1]);
    }
}

__global__ void k_node3_fb(const float* __restrict__ g2, const float* __restrict__ dis,
                           const float* __restrict__ b2, const float* __restrict__ sum2,
                           float* __restrict__ out, int N) {
    int i = gid();
    if (i < N) out[i] = dis[i] * (g2[i] + sum2[i]) + b2[0];
}

extern "C" void kernel_launch(void* const* d_in, const int* in_sizes, int n_in,
                              void* d_out, int out_size, void* d_ws, size_t ws_size,
                              hipStream_t stream) {
    const float* x  = (const float*)d_in[0];
    const int*   ei = (const int*)d_in[1];
    const float* W1 = (const float*)d_in[2];
    const float* b1 = (const float*)d_in[3];
    const float* W2 = (const float*)d_in[4];
    const float* b2 = (const float*)d_in[5];
    float* out = (float*)d_out;

    const int N = in_sizes[0];       // 100000
    const int E = in_sizes[1] / 2;   // 3200000
    const int H = in_sizes[2];       // 64
    const int NB = (N + CHUNK - 1) >> CHUNK_SHIFT;
    const int RG_CNT = (N + RG_SIZE - 1) >> RG_BITS;   // 13 for N=100K

    // overflow sanity: per-slice mean must be well under CAPB
    const int slice_mean = (E / SLICES) / (NB > 0 ? NB : 1);

    // workspace layout
    char* w = (char*)d_ws;
    unsigned* sorted = (unsigned*)w;   w += (size_t)NB * SLICES * CAPB * 4;
    int* len = (int*)w;                w += (size_t)NB * SLICES * 4;
    float* dis = (float*)w;            w += (size_t)N * 4;
    float* g   = (float*)w;            w += (size_t)N * 4;
    float* g2  = (float*)w;            w += (size_t)N * 4;
    size_t needed = (size_t)(w - (char*)d_ws);

    const int BLK = 256;
    const int nodeGrid = (N + BLK - 1) / BLK;

    if (N <= (1 << PACK_SHIFT) && NB <= NBMAX && H <= 64 && RG_CNT <= 16 &&
        slice_mean * 2 <= CAPB && ws_size >= needed) {
        k_place<<<SLICES, PLACE_TPB, 0, stream>>>(ei, ei + E, E, NB, len, sorted);
        k_acc1<<<NB, TPB, 0, stream>>>(sorted, len, x, dis, g, N);
        k_acc2<<<NB, TPB, 0, stream>>>(sorted, len, g, dis, W1, b1, W2, H, RG_CNT, g2, N);
        k_acc3<<<NB, TPB, 0, stream>>>(sorted, len, g2, dis, b2, RG_CNT, out, N);
    } else {
        // fallback: plain-atomic path (slow but correct)
        float* fdis = (float*)d_ws;
        float* fg   = fdis + N;
        float* fg2  = fg + N;
        float* ftmp = fg2 + N;
        float* fab  = ftmp + N;
        const int eGrid = (E + BLK - 1) / BLK;
        k_ab_fb<<<1, 64, 0, stream>>>(W1, b1, W2, fab, H);
        k_zero_f<<<nodeGrid, BLK, 0, stream>>>(ftmp, N);
        k_deg_fb<<<eGrid, BLK, 0, stream>>>(ei + E, ftmp, E);
        k_node1_fb<<<nodeGrid, BLK, 0, stream>>>(x, ftmp, fdis, fg, N);
        k_zero_f<<<nodeGrid, BLK, 0, stream>>>(ftmp, N);
        k_scat_fb<<<eGrid, BLK, 0, stream>>>(ei, fg, ftmp, E);
        k_node2_fb<<<nodeGrid, BLK, 0, stream>>>(fg, fdis, fab, ftmp, fg2, N);
        k_zero_f<<<nodeGrid, BLK, 0, stream>>>(ftmp, N);
        k_scat_fb<<<eGrid, BLK, 0, stream>>>(ei, fg2, ftmp, E);
        k_node3_fb<<<nodeGrid, BLK, 0, stream>>>(fg2, fdis, b2, ftmp, out, N);
    }
}

// Round 11
// 94.296 us; speedup vs baseline: 2.4020x; 2.4020x over previous
//
#include <hip/hip_runtime.h>
#include <math.h>

// GCN 2-layer on [N,1] collapses to scalar passes:
//   dis[i] = 1/sqrt(1 + indeg[i]);  g[i] = dis[i]*x[i]
//   s[c]   = dis[c]*(g[c] + sum_{e->c} g[row_e])
//   h[i]   = alpha*s[i] + beta   (alpha = W1.W2, beta = b1.W2)
//   g2[i]  = dis[i]*h[i]
//   out[c] = dis[c]*(g2[c] + sum_{e->c} g2[row_e]) + b2
//
// r11: acc kernels reverted to r9 (r10's row-group staging was a 2.2x loss:
// 13x LDS re-scan + occupancy drop; gathers to L2-resident arrays are cheap).
// k_place rewritten: block-local LDS-staged sort -> global writes are
// contiguous wave copies per bucket slice (was 3.2M scattered 4B stores).

#define CHUNK 256
#define CHUNK_SHIFT 8
#define PACK_SHIFT 17              // low 17 bits: row (N <= 131072)
#define ROW_MASK ((1u << PACK_SHIFT) - 1u)
#define NBMAX 512
#define SLICES 256                 // == k_place grid size
#define CAPB 80                    // slice capacity; mean 32, 8.5 sigma margin
#define CAPB_V (CAPB / 4)          // 20 uint4 slots per slice
#define TPB 512
#define PLACE_TPB 1024
#define STAGE_CAP 12544            // per-block edge stage (E/SLICES + margin)

static __device__ __forceinline__ int gid() {
    return blockIdx.x * blockDim.x + threadIdx.x;
}

// ---- place: LDS-staged counting sort, coalesced slice flush --------------
__global__ void __launch_bounds__(PLACE_TPB)
k_place(const int* __restrict__ row, const int* __restrict__ col,
        int E, int NB, int* __restrict__ len, unsigned* __restrict__ sorted) {
    __shared__ unsigned stage[STAGE_CAP];
    __shared__ int cnt[NBMAX];     // per-bucket count in this block's range
    __shared__ int soff[NBMAX];    // exclusive scan of cnt (stage offsets)
    __shared__ int wcnt[NBMAX];    // write cursors for phase 3
    const int tid = threadIdx.x;
    const int blk = blockIdx.x;
    int quads = E >> 2;
    int per = (quads + gridDim.x - 1) / gridDim.x;
    int qlo = blk * per, qhi = min(quads, qlo + per);

    for (int t = tid; t < NBMAX; t += PLACE_TPB) { cnt[t] = 0; wcnt[t] = 0; }
    __syncthreads();

    // phase 1: count
    for (int q = qlo + tid; q < qhi; q += PLACE_TPB) {
        int4 c = reinterpret_cast<const int4*>(col)[q];
        atomicAdd(&cnt[c.x >> CHUNK_SHIFT], 1);
        atomicAdd(&cnt[c.y >> CHUNK_SHIFT], 1);
        atomicAdd(&cnt[c.z >> CHUNK_SHIFT], 1);
        atomicAdd(&cnt[c.w >> CHUNK_SHIFT], 1);
    }
    if (blk == 0 && tid == 0)
        for (int j = quads << 2; j < E; ++j)
            atomicAdd(&cnt[col[j] >> CHUNK_SHIFT], 1);
    __syncthreads();

    // phase 2: inclusive scan -> exclusive offsets
    if (tid < NBMAX) soff[tid] = cnt[tid];
    __syncthreads();
    for (int o = 1; o < NBMAX; o <<= 1) {
        int v = 0;
        if (tid < NBMAX) {
            v = soff[tid];
            if (tid >= o) v += soff[tid - o];
        }
        __syncthreads();
        if (tid < NBMAX) soff[tid] = v;
        __syncthreads();
    }
    if (tid < NBMAX) soff[tid] -= cnt[tid];  // exclusive
    __syncthreads();

    // phase 3: re-read edges, pack into LDS grouped by bucket
    for (int q = qlo + tid; q < qhi; q += PLACE_TPB) {
        int4 r = reinterpret_cast<const int4*>(row)[q];
        int4 c = reinterpret_cast<const int4*>(col)[q];
        {
            int b = c.x >> CHUNK_SHIFT;
            int p = soff[b] + atomicAdd(&wcnt[b], 1);
            stage[p] = (unsigned)r.x | ((unsigned)(c.x & (CHUNK - 1)) << PACK_SHIFT);
        }
        {
            int b = c.y >> CHUNK_SHIFT;
            int p = soff[b] + atomicAdd(&wcnt[b], 1);
            stage[p] = (unsigned)r.y | ((unsigned)(c.y & (CHUNK - 1)) << PACK_SHIFT);
        }
        {
            int b = c.z >> CHUNK_SHIFT;
            int p = soff[b] + atomicAdd(&wcnt[b], 1);
            stage[p] = (unsigned)r.z | ((unsigned)(c.z & (CHUNK - 1)) << PACK_SHIFT);
        }
        {
            int b = c.w >> CHUNK_SHIFT;
            int p = soff[b] + atomicAdd(&wcnt[b], 1);
            stage[p] = (unsigned)r.w | ((unsigned)(c.w & (CHUNK - 1)) << PACK_SHIFT);
        }
    }
    if (blk == 0 && tid == 0) {
        for (int j = quads << 2; j < E; ++j) {
            int cc = col[j];
            int b = cc >> CHUNK_SHIFT;
            int p = soff[b] + atomicAdd(&wcnt[b], 1);
            stage[p] = (unsigned)row[j] | ((unsigned)(cc & (CHUNK - 1)) << PACK_SHIFT);
        }
    }
    __syncthreads();

    // phase 4: flush each bucket's run contiguously; write slice lengths
    const int wid = tid >> 6, lane = tid & 63;
    const int nw = PLACE_TPB >> 6;
    for (int b = wid; b < NB; b += nw) {
        int c = min(cnt[b], CAPB);
        int lb = soff[b];
        unsigned* dst = sorted + ((size_t)b * SLICES + blk) * CAPB;
        for (int i = lane; i < c; i += 64) dst[i] = stage[lb + i];
        if (lane == 0) len[(size_t)b * SLICES + blk] = c;
    }
}

// ---- fused accumulate + node passes (r9, proven) -------------------------

__global__ void __launch_bounds__(TPB)
k_acc1(const unsigned* __restrict__ sorted, const int* __restrict__ len,
       const float* __restrict__ x, float* __restrict__ dis, float* __restrict__ g,
       int N) {
    __shared__ float acc[CHUNK];
    __shared__ int slen[SLICES];
    const int b = blockIdx.x;
    const int tid = threadIdx.x;
    if (tid < CHUNK) acc[tid] = 0.0f;
    for (int t = tid; t < SLICES; t += TPB) slen[t] = len[(size_t)b * SLICES + t];
    __syncthreads();
    const uint4* bs = reinterpret_cast<const uint4*>(sorted + (size_t)b * SLICES * CAPB);
    const int TOTV = SLICES * CAPB_V;
    for (int j = tid; j < TOTV; j += TPB) {
        int s = j / CAPB_V;
        int l = slen[s];
        int base = (j - s * CAPB_V) << 2;
        if (base >= l) continue;
        uint4 p = bs[j];
        atomicAdd(&acc[p.x >> PACK_SHIFT], 1.0f);
        if (base + 1 < l) atomicAdd(&acc[p.y >> PACK_SHIFT], 1.0f);
        if (base + 2 < l) atomicAdd(&acc[p.z >> PACK_SHIFT], 1.0f);
        if (base + 3 < l) atomicAdd(&acc[p.w >> PACK_SHIFT], 1.0f);
    }
    __syncthreads();
    int i = b * CHUNK + tid;
    if (tid < CHUNK && i < N) {
        float d = rsqrtf(1.0f + acc[tid]);  // +1: self-loop
        dis[i] = d;
        g[i] = d * x[i];
    }
}

__global__ void __launch_bounds__(TPB)
k_acc2(const unsigned* __restrict__ sorted, const int* __restrict__ len,
       const float* __restrict__ g, const float* __restrict__ dis,
       const float* __restrict__ W1, const float* __restrict__ b1,
       const float* __restrict__ W2, int H,
       float* __restrict__ g2, int N) {
    __shared__ float acc[CHUNK];
    __shared__ int slen[SLICES];
    __shared__ float sab[2];
    const int b = blockIdx.x;
    const int tid = threadIdx.x;
    if (tid < CHUNK) acc[tid] = 0.0f;
    for (int t = tid; t < SLICES; t += TPB) slen[t] = len[(size_t)b * SLICES + t];
    if (tid >= CHUNK && tid < CHUNK + 64) {  // one wave: alpha, beta (H<=64)
        int t = tid - CHUNK;
        float w2 = (t < H) ? W2[t] : 0.0f;
        float a = (t < H) ? W1[t] * w2 : 0.0f;
        float bb = (t < H) ? b1[t] * w2 : 0.0f;
        for (int o = 32; o; o >>= 1) {
            a += __shfl_down(a, o, 64);
            bb += __shfl_down(bb, o, 64);
        }
        if (t == 0) { sab[0] = a; sab[1] = bb; }
    }
    __syncthreads();
    const uint4* bs = reinterpret_cast<const uint4*>(sorted + (size_t)b * SLICES * CAPB);
    const int TOTV = SLICES * CAPB_V;
    for (int j = tid; j < TOTV; j += TPB) {
        int s = j / CAPB_V;
        int l = slen[s];
        int base = (j - s * CAPB_V) << 2;
        if (base >= l) continue;
        uint4 p = bs[j];
        atomicAdd(&acc[p.x >> PACK_SHIFT], g[p.x & ROW_MASK]);
        if (base + 1 < l) atomicAdd(&acc[p.y >> PACK_SHIFT], g[p.y & ROW_MASK]);
        if (base + 2 < l) atomicAdd(&acc[p.z >> PACK_SHIFT], g[p.z & ROW_MASK]);
        if (base + 3 < l) atomicAdd(&acc[p.w >> PACK_SHIFT], g[p.w & ROW_MASK]);
    }
    __syncthreads();
    int i = b * CHUNK + tid;
    if (tid < CHUNK && i < N) {
        float d = dis[i];
        float s = d * (g[i] + acc[tid]);
        g2[i] = d * (sab[0] * s + sab[1]);
    }
}

__global__ void __launch_bounds__(TPB)
k_acc3(const unsigned* __restrict__ sorted, const int* __restrict__ len,
       const float* __restrict__ g2, const float* __restrict__ dis,
       const float* __restrict__ b2, float* __restrict__ out, int N) {
    __shared__ float acc[CHUNK];
    __shared__ int slen[SLICES];
    const int b = blockIdx.x;
    const int tid = threadIdx.x;
    if (tid < CHUNK) acc[tid] = 0.0f;
    for (int t = tid; t < SLICES; t += TPB) slen[t] = len[(size_t)b * SLICES + t];
    __syncthreads();
    const uint4* bs = reinterpret_cast<const uint4*>(sorted + (size_t)b * SLICES * CAPB);
    const int TOTV = SLICES * CAPB_V;
    for (int j = tid; j < TOTV; j += TPB) {
        int s = j / CAPB_V;
        int l = slen[s];
        int base = (j - s * CAPB_V) << 2;
        if (base >= l) continue;
        uint4 p = bs[j];
        atomicAdd(&acc[p.x >> PACK_SHIFT], g2[p.x & ROW_MASK]);
        if (base + 1 < l) atomicAdd(&acc[p.y >> PACK_SHIFT], g2[p.y & ROW_MASK]);
        if (base + 2 < l) atomicAdd(&acc[p.z >> PACK_SHIFT], g2[p.z & ROW_MASK]);
        if (base + 3 < l) atomicAdd(&acc[p.w >> PACK_SHIFT], g2[p.w & ROW_MASK]);
    }
    __syncthreads();
    int i = b * CHUNK + tid;
    if (tid < CHUNK && i < N)
        out[i] = dis[i] * (g2[i] + acc[tid]) + b2[0];
}

// ---- fallback (plain device atomics, known-correct) ----------------------

__global__ void k_zero_f(float* __restrict__ p, int n) {
    int i = gid();
    if (i < n) p[i] = 0.0f;
}

__global__ void k_ab_fb(const float* __restrict__ W1, const float* __restrict__ b1,
                        const float* __restrict__ W2, float* __restrict__ ab, int hidden) {
    int t = threadIdx.x;
    float w2 = (t < hidden) ? W2[t] : 0.0f;
    float a = (t < hidden) ? W1[t] * w2 : 0.0f;
    float b = (t < hidden) ? b1[t] * w2 : 0.0f;
    for (int o = 32; o; o >>= 1) {
        a += __shfl_down(a, o, 64);
        b += __shfl_down(b, o, 64);
    }
    if (t == 0) { ab[0] = a; ab[1] = b; }
}

__global__ void k_deg_fb(const int* __restrict__ col, float* __restrict__ t, int E) {
    int i = gid();
    if (i < E) atomicAdd(&t[col[i]], 1.0f);
}

__global__ void k_scat_fb(const int* __restrict__ ei, const float* __restrict__ val,
                          float* __restrict__ t, int E) {
    int i = gid();
    if (i < E) atomicAdd(&t[ei[E + i]], val[ei[i]]);
}

__global__ void k_node1_fb(const float* __restrict__ x, const float* __restrict__ degsum,
                           float* __restrict__ dis, float* __restrict__ g, int N) {
    int i = gid();
    if (i < N) {
        float d = rsqrtf(1.0f + degsum[i]);
        dis[i] = d;
        g[i] = d * x[i];
    }
}

__global__ void k_node2_fb(const float* __restrict__ g, const float* __restrict__ dis,
                           const float* __restrict__ ab, const float* __restrict__ sum1,
                           float* __restrict__ g2, int N) {
    int i = gid();
    if (i < N) {
        float s = dis[i] * (g[i] + sum1[i]);
        g2[i] = dis[i] * (ab[0] * s + ab[1]);
    }
}

__global__ void k_node3_fb(const float* __restrict__ g2, const float* __restrict__ dis,
                           const float* __restrict__ b2, const float* __restrict__ sum2,
                           float* __restrict__ out, int N) {
    int i = gid();
    if (i < N) out[i] = dis[i] * (g2[i] + sum2[i]) + b2[0];
}

extern "C" void kernel_launch(void* const* d_in, const int* in_sizes, int n_in,
                              void* d_out, int out_size, void* d_ws, size_t ws_size,
                              hipStream_t stream) {
    const float* x  = (const float*)d_in[0];
    const int*   ei = (const int*)d_in[1];
    const float* W1 = (const float*)d_in[2];
    const float* b1 = (const float*)d_in[3];
    const float* W2 = (const float*)d_in[4];
    const float* b2 = (const float*)d_in[5];
    float* out = (float*)d_out;

    const int N = in_sizes[0];       // 100000
    const int E = in_sizes[1] / 2;   // 3200000
    const int H = in_sizes[2];       // 64
    const int NB = (N + CHUNK - 1) >> CHUNK_SHIFT;

    // per-block stage bound: edges per place block + tail margin
    const int per_quads = ((E >> 2) + SLICES - 1) / SLICES;
    const int stage_need = per_quads * 4 + 8;

    // overflow sanity: per-slice mean must be well under CAPB
    const int slice_mean = (E / SLICES) / (NB > 0 ? NB : 1);

    // workspace layout
    char* w = (char*)d_ws;
    unsigned* sorted = (unsigned*)w;   w += (size_t)NB * SLICES * CAPB * 4;
    int* len = (int*)w;                w += (size_t)NB * SLICES * 4;
    float* dis = (float*)w;            w += (size_t)N * 4;
    float* g   = (float*)w;            w += (size_t)N * 4;
    float* g2  = (float*)w;            w += (size_t)N * 4;
    size_t needed = (size_t)(w - (char*)d_ws);

    const int BLK = 256;
    const int nodeGrid = (N + BLK - 1) / BLK;

    if (N <= (1 << PACK_SHIFT) && NB <= NBMAX && H <= 64 &&
        stage_need <= STAGE_CAP && slice_mean * 2 <= CAPB && ws_size >= needed) {
        k_place<<<SLICES, PLACE_TPB, 0, stream>>>(ei, ei + E, E, NB, len, sorted);
        k_acc1<<<NB, TPB, 0, stream>>>(sorted, len, x, dis, g, N);
        k_acc2<<<NB, TPB, 0, stream>>>(sorted, len, g, dis, W1, b1, W2, H, g2, N);
        k_acc3<<<NB, TPB, 0, stream>>>(sorted, len, g2, dis, b2, out, N);
    } else {
        // fallback: plain-atomic path (slow but correct)
        float* fdis = (float*)d_ws;
        float* fg   = fdis + N;
        float* fg2  = fg + N;
        float* ftmp = fg2 + N;
        float* fab  = ftmp + N;
        const int eGrid = (E + BLK - 1) / BLK;
        k_ab_fb<<<1, 64, 0, stream>>>(W1, b1, W2, fab, H);
        k_zero_f<<<nodeGrid, BLK, 0, stream>>>(ftmp, N);
        k_deg_fb<<<eGrid, BLK, 0, stream>>>(ei + E, ftmp, E);
        k_node1_fb<<<nodeGrid, BLK, 0, stream>>>(x, ftmp, fdis, fg, N);
        k_zero_f<<<nodeGrid, BLK, 0, stream>>>(ftmp, N);
        k_scat_fb<<<eGrid, BLK, 0, stream>>>(ei, fg, ftmp, E);
        k_node2_fb<<<nodeGrid, BLK, 0, stream>>>(fg, fdis, fab, ftmp, fg2, N);
        k_zero_f<<<nodeGrid, BLK, 0, stream>>>(ftmp, N);
        k_scat_fb<<<eGrid, BLK, 0, stream>>>(ei, fg2, ftmp, E);
        k_node3_fb<<<nodeGrid, BLK, 0, stream>>>(fg2, fdis, b2, ftmp, out, N);
    }
}